// Round 6
// baseline (356.893 us; speedup 1.0000x reference)
//
#include <hip/hip_runtime.h>

#define BB    8
#define CC    64
#define NN    2048
#define GG    2048
#define MFREQ 4032

typedef __attribute__((ext_vector_type(4))) float f32x4;
typedef __attribute__((ext_vector_type(8))) short bf16x8;

static __device__ __forceinline__ unsigned short f2bf(float f) {
    union { float f; unsigned u; } v; v.f = f;
    unsigned r = v.u + 0x7fff + ((v.u >> 16) & 1);   // RNE
    return (unsigned short)(r >> 16);
}

#define ASYNC_COPY16(gp, lp)                                                        \
    __builtin_amdgcn_global_load_lds(                                               \
        (const __attribute__((address_space(1))) unsigned int*)(gp),                \
        (__attribute__((address_space(3))) unsigned int*)(lp), 16, 0, 0)

// ---------------------------------------------------------------------------
// Fused streaming packs, 4 units/thread for memory-level parallelism.
// Unit space (1 unit = 1 float4 -> 4 bf16):
//  [0, 2097152)       : Af [4096 x 2048]
//  [2097152, 2359296) : Xb [512 x 2048]
//  [2359296, 6553600) : Mi [2048 x 8192]  (Hermitian fold)
// mode: 0=copy 1=negate 2=reverse 3=zero
__global__ __launch_bounds__(256) void pack_all(const float* __restrict__ vf_re,
                                                const float* __restrict__ vf_im,
                                                const float* __restrict__ x,
                                                const float* __restrict__ vi_re,
                                                const float* __restrict__ vi_im,
                                                unsigned short* __restrict__ af,
                                                unsigned short* __restrict__ xb,
                                                unsigned short* __restrict__ mi) {
    const int t = threadIdx.x;
    size_t u0 = (size_t)blockIdx.x * 1024 + t;

    const float* sp[4];
    unsigned short* dp[4];
    int md[4];

    #pragma unroll
    for (int j = 0; j < 4; ++j) {
        size_t u = u0 + (size_t)j * 256;
        if (u < 2097152) {
            int m = (int)(u >> 9);
            int q = ((int)u & 511) * 4;
            int g = m & 2047;
            int f = (g >> 5) * 63 + (g & 31);
            sp[j] = (m < 2048 ? vf_re : vf_im) + (size_t)f * 2048 + q;
            md[j] = 0;
            dp[j] = af + (size_t)m * 2048 + q;
        } else if (u < 2359296) {
            size_t q = (u - 2097152) * 4;
            sp[j] = x + q;
            md[j] = 0;
            dp[j] = xb + q;
        } else {
            size_t r = u - 2359296;
            int n = (int)(r >> 11);
            int q4 = ((int)r & 2047) * 4;
            int region = q4 >> 11;
            int off = q4 & 2047;
            dp[j] = mi + (size_t)n * 8192 + q4;
            if (region == 0)      { sp[j] = vi_re + (size_t)n * MFREQ + off; md[j] = 0; }
            else if (region == 1) { sp[j] = vi_im + (size_t)n * MFREQ + off; md[j] = 1; }
            else if (off < 64)    { sp[j] = vi_re; md[j] = 3; }
            else {
                sp[j] = (region == 2 ? vi_re : vi_im) + (size_t)n * MFREQ + (4092 - off);
                md[j] = 2;
            }
        }
    }

    float4 v[4];
    #pragma unroll
    for (int j = 0; j < 4; ++j)
        v[j] = (md[j] == 3) ? make_float4(0.f, 0.f, 0.f, 0.f) : *(const float4*)sp[j];

    #pragma unroll
    for (int j = 0; j < 4; ++j) {
        float4 w = v[j];
        ushort4 o;
        if (md[j] == 1) { o.x = f2bf(-w.x); o.y = f2bf(-w.y); o.z = f2bf(-w.z); o.w = f2bf(-w.w); }
        else if (md[j] == 2) { o.x = f2bf(w.w); o.y = f2bf(w.z); o.z = f2bf(w.y); o.w = f2bf(w.x); }
        else { o.x = f2bf(w.x); o.y = f2bf(w.y); o.z = f2bf(w.z); o.w = f2bf(w.w); }
        *(ushort4*)dp[j] = o;
    }
}

// Transpose weights: wt[g][io] = packed bf16 (re | im<<16)
__global__ __launch_bounds__(256) void pack_wt(const float* __restrict__ w1_re,
                                               const float* __restrict__ w1_im,
                                               const float* __restrict__ w2_re,
                                               const float* __restrict__ w2_im,
                                               unsigned int* __restrict__ wt) {
    __shared__ float sre[64][65];
    __shared__ float sim[64][65];
    int wsel = blockIdx.z;
    const float* wre = wsel ? w2_re : w1_re;
    const float* wim = wsel ? w2_im : w1_im;
    int io0 = blockIdx.y * 64, xy0 = blockIdx.x * 64;
    int t = threadIdx.x;
    int r = t >> 2, cq = (t & 3) * 16;
    for (int j = 0; j < 16; j += 4) {
        float4 a = *(const float4*)(wre + (size_t)(io0 + r) * 1024 + xy0 + cq + j);
        float4 b = *(const float4*)(wim + (size_t)(io0 + r) * 1024 + xy0 + cq + j);
        sre[r][cq + j + 0] = a.x; sre[r][cq + j + 1] = a.y; sre[r][cq + j + 2] = a.z; sre[r][cq + j + 3] = a.w;
        sim[r][cq + j + 0] = b.x; sim[r][cq + j + 1] = b.y; sim[r][cq + j + 2] = b.z; sim[r][cq + j + 3] = b.w;
    }
    __syncthreads();
    int iol = t & 63, gq = t >> 6;
    for (int jj = 0; jj < 16; ++jj) {
        int gl = jj * 4 + gq;
        int g = xy0 + gl + wsel * 1024;
        unsigned int o = (unsigned int)f2bf(sre[iol][gl]) | ((unsigned int)f2bf(sim[iol][gl]) << 16);
        wt[(size_t)g * 4096 + io0 + iol] = o;
    }
}

// phi[b][g] = sum_e m{1,2}[xy][e] * emb[b][e]
__global__ __launch_bounds__(256) void phi_k(const float* __restrict__ m1_re,
                                             const float* __restrict__ m1_im,
                                             const float* __restrict__ m2_re,
                                             const float* __restrict__ m2_im,
                                             const float* __restrict__ emb,
                                             float* __restrict__ phi_re,
                                             float* __restrict__ phi_im) {
    int g = blockIdx.x, b = blockIdx.y, e = threadIdx.x;
    int xy = g & 1023;
    const float* mr = (g < 1024 ? m1_re : m2_re) + xy * 256;
    const float* mi = (g < 1024 ? m1_im : m2_im) + xy * 256;
    float em = emb[b * 256 + e];
    float pr = mr[e] * em, pi = mi[e] * em;
    __shared__ float sr[4], si[4];
    for (int s = 32; s > 0; s >>= 1) { pr += __shfl_down(pr, s); pi += __shfl_down(pi, s); }
    int wid = e >> 6;
    if ((e & 63) == 0) { sr[wid] = pr; si[wid] = pi; }
    __syncthreads();
    if (e == 0) {
        phi_re[b * 2048 + g] = sr[0] + sr[1] + sr[2] + sr[3];
        phi_im[b * 2048 + g] = si[0] + si[1] + si[2] + si[3];
    }
}

// ---------------------------------------------------------------------------
// Split-K MFMA GEMM: P[z] = A[M][Kslice] @ B[N][Kslice]^T
// ilv=1 (forward only): store (rr,cc) at ((rr&2047)*1024 + cc*2 + (rr>>11)).
__global__ __launch_bounds__(256, 3) void gemm_sk(const unsigned short* __restrict__ A,
                                                  const unsigned short* __restrict__ Bm,
                                                  float* __restrict__ P,
                                                  int M, int N, int K, int Kper, int ilv) {
    __shared__ unsigned short As[128 * 64];
    __shared__ unsigned short Bs[128 * 64];
    int t = threadIdx.x;
    int lane = t & 63, w = t >> 6;
    int m0 = blockIdx.y * 128, n0 = blockIdx.x * 128;
    int z = blockIdx.z;
    int kbase = z * Kper;
    int wm = (w >> 1) * 64, wn = (w & 1) * 64;
    int lr = lane & 15, quad = lane >> 4;
    int rsub = lane >> 3, slot = lane & 7;

    f32x4 acc[4][4] = {};

    for (int kk = kbase; kk < kbase + Kper; kk += 64) {
        __syncthreads();
        #pragma unroll
        for (int l = 0; l < 4; ++l) {
            int r = (w * 4 + l) * 8 + rsub;
            int c = slot ^ (r & 7);
            ASYNC_COPY16(A + (size_t)(m0 + r) * K + kk + c * 8, As + r * 64 + slot * 8);
            ASYNC_COPY16(Bm + (size_t)(n0 + r) * K + kk + c * 8, Bs + r * 64 + slot * 8);
        }
        __syncthreads();
        #pragma unroll
        for (int ks = 0; ks < 2; ++ks) {
            bf16x8 af[4], bfr[4];
            #pragma unroll
            for (int i = 0; i < 4; ++i) {
                int row = wm + i * 16 + lr;
                int q = (ks * 4 + quad) ^ (row & 7);
                af[i] = *(const bf16x8*)(As + row * 64 + q * 8);
                int rowb = wn + i * 16 + lr;
                int qb = (ks * 4 + quad) ^ (rowb & 7);
                bfr[i] = *(const bf16x8*)(Bs + rowb * 64 + qb * 8);
            }
            #pragma unroll
            for (int i = 0; i < 4; ++i)
            #pragma unroll
            for (int j = 0; j < 4; ++j)
                acc[i][j] = __builtin_amdgcn_mfma_f32_16x16x32_bf16(af[i], bfr[j], acc[i][j], 0, 0, 0);
        }
    }
    float* Pz = P + (size_t)z * M * N;
    size_t rstride = ilv ? 1024 : (size_t)N;
    #pragma unroll
    for (int i = 0; i < 4; ++i)
    #pragma unroll
    for (int j = 0; j < 4; ++j) {
        int rr = m0 + wm + i * 16 + quad * 4;
        int cc = n0 + wn + j * 16 + lr;
        size_t base = ilv ? ((size_t)(rr & 2047) * 1024 + cc * 2 + (rr >> 11))
                          : ((size_t)rr * N + cc);
        float* cp = Pz + base;
        f32x4 v = acc[i][j];
        cp[0]           = v.x;
        cp[rstride]     = v.y;
        cp[2 * rstride] = v.z;
        cp[3 * rstride] = v.w;
    }
}

// Sum split-K partials: out[i] = alpha * sum_z P[z][i]
__global__ __launch_bounds__(256) void reduce_k(const float* __restrict__ P,
                                                float* __restrict__ out,
                                                int S, size_t elems, float alpha) {
    size_t idx = ((size_t)blockIdx.x * 256 + threadIdx.x) * 4;
    float4 s = *(const float4*)(P + idx);
    for (int zz = 1; zz < S; ++zz) {
        float4 v = *(const float4*)(P + (size_t)zz * elems + idx);
        s.x += v.x; s.y += v.y; s.z += v.z; s.w += v.w;
    }
    s.x *= alpha; s.y *= alpha; s.z *= alpha; s.w *= alpha;
    *(float4*)(out + idx) = s;
}

// ---------------------------------------------------------------------------
// Middle: g-tile 2, grid 1024 (4 blocks/CU). All staging up front, one barrier.
__global__ __launch_bounds__(256, 4) void middle_k(const float* __restrict__ O1,
                                                   const unsigned int* __restrict__ wt,
                                                   const float* __restrict__ phi_re,
                                                   const float* __restrict__ phi_im,
                                                   unsigned short* __restrict__ Yt) {
    __shared__ unsigned int sW[2][4096];
    __shared__ float sInc[2][1024];
    int t = threadIdx.x;
    int g0 = blockIdx.x * 2;
    int b = t >> 5, p = t & 31;

    #pragma unroll
    for (int gt = 0; gt < 2; ++gt) {
        int g = g0 + gt;
        #pragma unroll
        for (int j = 0; j < 4; ++j)
            ASYNC_COPY16(wt + (size_t)g * 4096 + (j * 256 + t) * 4, &sW[gt][(j * 256 + t) * 4]);
        ASYNC_COPY16(O1 + (size_t)g * 1024 + t * 4, &sInc[gt][t * 4]);
    }
    __syncthreads();

    unsigned short reA[2][2], imA[2][2];

    #pragma unroll
    for (int gt = 0; gt < 2; ++gt) {
        int g = g0 + gt;
        float ar0 = 0.f, ai0 = 0.f, ar1 = 0.f, ai1 = 0.f;
        const float2* incp = (const float2*)sInc[gt] + b * 64;
        const unsigned int* wp = sW[gt] + 2 * p;
        #pragma unroll 8
        for (int i = 0; i < 64; ++i) {
            float2 a = incp[i];
            uint2 uu = *(const uint2*)(wp + i * 64);
            float w0r = __uint_as_float(uu.x << 16);
            float w0i = __uint_as_float(uu.x & 0xffff0000u);
            float w1r = __uint_as_float(uu.y << 16);
            float w1i = __uint_as_float(uu.y & 0xffff0000u);
            ar0 += a.x * w0r - a.y * w0i;  ai0 += a.x * w0i + a.y * w0r;
            ar1 += a.x * w1r - a.y * w1i;  ai1 += a.x * w1i + a.y * w1r;
        }
        float pr = phi_re[b * 2048 + g], pi = phi_im[b * 2048 + g];
        reA[0][gt] = f2bf(pr * ar0 - pi * ai0);
        imA[0][gt] = f2bf(pr * ai0 + pi * ar0);
        reA[1][gt] = f2bf(pr * ar1 - pi * ai1);
        imA[1][gt] = f2bf(pr * ai1 + pi * ar1);
    }

    #pragma unroll
    for (int ch = 0; ch < 2; ++ch) {
        int c = 2 * p + ch;
        size_t r0 = (size_t)(b * 64 + c) * 8192;
        size_t rf = (size_t)(b * 64 + 63 - c) * 8192;
        unsigned int ure = (unsigned int)reA[ch][0] | ((unsigned int)reA[ch][1] << 16);
        unsigned int uim = (unsigned int)imA[ch][0] | ((unsigned int)imA[ch][1] << 16);
        *(unsigned int*)(Yt + r0 + g0)        = ure;
        *(unsigned int*)(Yt + r0 + 2048 + g0) = uim;
        *(unsigned int*)(Yt + rf + 4096 + g0) = ure;
        *(unsigned int*)(Yt + rf + 6144 + g0) = uim;
    }
}

// ---------------------------------------------------------------------------
extern "C" void kernel_launch(void* const* d_in, const int* in_sizes, int n_in,
                              void* d_out, int out_size, void* d_ws, size_t ws_size,
                              hipStream_t stream) {
    const float* x     = (const float*)d_in[0];
    const float* emb   = (const float*)d_in[1];
    const float* vf_re = (const float*)d_in[2];
    const float* vf_im = (const float*)d_in[3];
    const float* vi_re = (const float*)d_in[4];
    const float* vi_im = (const float*)d_in[5];
    const float* w1_re = (const float*)d_in[6];
    const float* w1_im = (const float*)d_in[7];
    const float* w2_re = (const float*)d_in[8];
    const float* w2_im = (const float*)d_in[9];
    const float* m1_re = (const float*)d_in[10];
    const float* m1_im = (const float*)d_in[11];
    const float* m2_re = (const float*)d_in[12];
    const float* m2_im = (const float*)d_in[13];

    char* ws = (char*)d_ws;
    unsigned short* Af = (unsigned short*)(ws);                 // 16,777,216
    unsigned short* Xb = (unsigned short*)(ws + 16777216);      //  2,097,152
    unsigned short* Mi = (unsigned short*)(ws + 18874368);      // 33,554,432
    unsigned int*   Wt = (unsigned int*)(ws + 52428800);        // 33,554,432
    float*          O1 = (float*)(ws + 85983232);               //  8,388,608 (interleaved)
    float*       PhiRe = (float*)(ws + 94371840);               //     65,536
    float*       PhiIm = (float*)(ws + 94437376);               //     65,536
    unsigned short* Yt = (unsigned short*)(ws + 94502912);      //  8,388,608
    float*          P  = (float*)(ws + 102891520);              // 67,108,864 partials -> 170,000,384
    float* out = (float*)d_out;

    pack_all<<<6400, 256, 0, stream>>>(vf_re, vf_im, x, vi_re, vi_im, Af, Xb, Mi);
    pack_wt<<<dim3(16, 64, 2), 256, 0, stream>>>(w1_re, w1_im, w2_re, w2_im, Wt);
    phi_k<<<dim3(2048, 8), 256, 0, stream>>>(m1_re, m1_im, m2_re, m2_im, emb, PhiRe, PhiIm);

    // Forward: O1(ilv) = Af[4096x2048] @ Xb[512x2048]^T, split-K 8 -> 1024 blocks
    gemm_sk<<<dim3(4, 32, 8), 256, 0, stream>>>(Af, Xb, P, 4096, 512, 2048, 256, 1);
    reduce_k<<<2048, 256, 0, stream>>>(P, O1, 8, (size_t)4096 * 512, 1.0f);

    middle_k<<<1024, 256, 0, stream>>>(O1, Wt, PhiRe, PhiIm, Yt);

    // Inverse: out[512][2048] = (2/N) * Yt[512x8192] @ Mi[2048x8192]^T, split-K 16 -> 1024 blocks
    gemm_sk<<<dim3(16, 4, 16), 256, 0, stream>>>(Yt, Mi, P, 512, 2048, 8192, 512, 0);
    reduce_k<<<1024, 256, 0, stream>>>(P, out, 16, (size_t)512 * 2048, 1.0f / 1024.0f);
}